// Round 4
// baseline (1569.171 us; speedup 1.0000x reference)
//
#include <hip/hip_runtime.h>
#include <hip/hip_bf16.h>
#include <math.h>

typedef unsigned short u16;
typedef unsigned int   u32;
typedef unsigned long long u64;

#define DEV static __device__ __forceinline__

static constexpr int LL = 128, DD = 512, HH = 256, KK = 5, NN = 1024;

// workspace byte offsets
static constexpr size_t OFF_QP   = 0;         // 512 f32
static constexpr size_t OFF_U    = 4096;      // 512 f32
static constexpr size_t OFF_SC   = 8192;      // 1024 f32
static constexpr size_t OFF_WSC  = 12288;     // 5 f32
static constexpr size_t OFF_IDX  = 12416;     // 5 int
static constexpr size_t OFF_HG   = 16384;     // [2 layer][2 dir][2 parity][1280] u64 = 80KB
static constexpr size_t OFF_X0   = 98304;     // [640][512] f32 = 1310720
static constexpr size_t OFF_PRE  = 1409024;   // [2][640][1024] f32 = 5242880
static constexpr size_t OFF_OUT0 = 6651904;   // [640][512] f32 = 1310720
static constexpr size_t OFF_OUT1 = 7962624;   // [640][512] f32 = 1310720

DEV float sigf(float x){ return 1.0f/(1.0f + expf(-x)); }

// ---------------- query projection: qp = Wq @ q + bq  (grid 4 x 128) ----------------
__global__ void k_qproj(const float* __restrict__ Wq, const float* __restrict__ q,
                        const float* __restrict__ bq, float* __restrict__ qp) {
  __shared__ float qs[512];
  int tid = threadIdx.x;
  for (int f = tid; f < 512; f += 128) qs[f] = q[f];
  __syncthreads();
  int row = blockIdx.x * 128 + tid;
  const float* wr = Wq + (size_t)row * 512;
  float acc = 0.f;
  for (int j = 0; j < 512; j += 4) {
    float4 w = *(const float4*)(wr + j);
    acc += w.x*qs[j] + w.y*qs[j+1] + w.z*qs[j+2] + w.w*qs[j+3];
  }
  qp[row] = acc + bq[row];
}

// ---------------- u = Wk^T @ qp  (grid 4 x 128; bk.qp dropped: rank-invariant) ------
__global__ void k_keyvec(const float* __restrict__ Wk, const float* __restrict__ qp,
                         float* __restrict__ u) {
  __shared__ float qs[512];
  int tid = threadIdx.x;
  for (int f = tid; f < 512; f += 128) qs[f] = qp[f];
  __syncthreads();
  int col = blockIdx.x * 128 + tid;
  float acc = 0.f;
  #pragma unroll 4
  for (int j = 0; j < 512; ++j) acc += Wk[(size_t)j*512 + col] * qs[j];
  u[col] = acc;
}

// ---------------- scores[n] ~ sum_{l,d} ep[n,l,d]*u[d]  (scale/shift dropped) -------
__global__ void k_scores(const float* __restrict__ ep, const float* __restrict__ u,
                         float* __restrict__ scores) {
  __shared__ float red[256];
  int tid = threadIdx.x, n = blockIdx.x;
  int d0 = (tid * 4) & 511;
  float u0 = u[d0+0], u1 = u[d0+1], u2 = u[d0+2], u3 = u[d0+3];
  const float* base = ep + (size_t)n * (LL*DD);
  float acc = 0.f;
  for (int c = tid; c < (LL*DD)/4; c += 256) {
    float4 v = *(const float4*)(base + (size_t)c*4);
    acc += v.x*u0 + v.y*u1 + v.z*u2 + v.w*u3;
  }
  red[tid] = acc;
  __syncthreads();
  for (int off = 128; off > 0; off >>= 1) { if (tid < off) red[tid] += red[tid+off]; __syncthreads(); }
  if (tid == 0) scores[n] = red[0];
}

// ---------------- top-5 + age weights ----------------
__global__ void k_topk(const float* __restrict__ scores, const float* __restrict__ ages,
                       int* __restrict__ idx5, float* __restrict__ wsc) {
  __shared__ float s0[NN];
  __shared__ float sv[NN];
  __shared__ int   si[NN];
  __shared__ int   chosen[KK];
  int tid = threadIdx.x;                 // 1024 threads
  s0[tid] = scores[tid];
  __syncthreads();
  for (int r = 0; r < KK; ++r) {
    float v = s0[tid];
    for (int m = 0; m < r; ++m) if (chosen[m] == tid) v = -3.4e38f;
    sv[tid] = v; si[tid] = tid;
    __syncthreads();
    for (int off = 512; off > 0; off >>= 1) {
      if (tid < off) {
        float a = sv[tid], b = sv[tid+off];
        int ia = si[tid], ib = si[tid+off];
        if (b > a || (b == a && ib < ia)) { sv[tid] = b; si[tid] = ib; }
      }
      __syncthreads();
    }
    if (tid == 0) {
      int w = si[0];
      chosen[r] = w;
      idx5[r] = w;
      wsc[r] = 1.0f / (1.0f + ages[w] * 0.01f);
    }
    __syncthreads();
  }
}

// ---------------- x0[(t*5+b)][i] = ep[idx[b],t,i] * wsc[b]  (grid 128 x 256) --------
__global__ void k_gather(const float* __restrict__ ep, const int* __restrict__ idx5,
                         const float* __restrict__ wsc, float* __restrict__ x0) {
  int t = blockIdx.x, tid = threadIdx.x;
  for (int f = tid; f < 5*512; f += 256) {
    int b = f >> 9, i = f & 511;
    x0[((size_t)t*5 + b)*512 + i] = ep[((size_t)idx5[b]*LL + t)*512 + i] * wsc[b];
  }
}

// ---------------- pre-projection GEMM: pre[dir][m][g] = A[m,:] . W[g,:] + bias ------
// A [640][512] (m = t*5+b), W = w_ih [1024][512]. Tiles M32 x G64, 256 threads,
// register tile 2m x 4g, LDS pad 36 (lane-stride-1 g-mapping -> <=2-way conflicts).
__global__ __launch_bounds__(256) void k_pre(
    const float* __restrict__ A,
    const float* __restrict__ WF, const float* __restrict__ WB,
    const float* __restrict__ bihF, const float* __restrict__ bhhF,
    const float* __restrict__ bihB, const float* __restrict__ bhhB,
    float* __restrict__ pre) {
  int bx = blockIdx.x, by = blockIdx.y, dir = blockIdx.z;
  int tid = threadIdx.x;
  int tx = tid & 15, ty = tid >> 4;
  const float* W   = dir ? WB   : WF;
  const float* bih = dir ? bihB : bihF;
  const float* bhh = dir ? bhhB : bhhF;
  __shared__ __align__(16) float As[32][36];
  __shared__ __align__(16) float Bs[64][36];
  int mtile = by*32, gtile = bx*64;
  float acc00=0,acc01=0,acc02=0,acc03=0, acc10=0,acc11=0,acc12=0,acc13=0;
  int srow = tid >> 3, sc4 = (tid & 7) * 4;
  for (int kt = 0; kt < 16; ++kt) {
    int k0 = kt*32;
    float4 av  = *(const float4*)&A[(size_t)(mtile + srow)*512 + k0 + sc4];
    float4 bv0 = *(const float4*)&W[(size_t)(gtile + srow)*512 + k0 + sc4];
    float4 bv1 = *(const float4*)&W[(size_t)(gtile + srow + 32)*512 + k0 + sc4];
    __syncthreads();
    *(float4*)&As[srow][sc4]    = av;
    *(float4*)&Bs[srow][sc4]    = bv0;
    *(float4*)&Bs[srow+32][sc4] = bv1;
    __syncthreads();
    #pragma unroll
    for (int k4 = 0; k4 < 8; ++k4) {
      float4 a0 = *(const float4*)&As[ty][k4*4];
      float4 a1 = *(const float4*)&As[ty+16][k4*4];
      float4 b0 = *(const float4*)&Bs[tx][k4*4];
      float4 b1 = *(const float4*)&Bs[tx+16][k4*4];
      float4 b2 = *(const float4*)&Bs[tx+32][k4*4];
      float4 b3 = *(const float4*)&Bs[tx+48][k4*4];
      acc00 += a0.x*b0.x + a0.y*b0.y + a0.z*b0.z + a0.w*b0.w;
      acc01 += a0.x*b1.x + a0.y*b1.y + a0.z*b1.z + a0.w*b1.w;
      acc02 += a0.x*b2.x + a0.y*b2.y + a0.z*b2.z + a0.w*b2.w;
      acc03 += a0.x*b3.x + a0.y*b3.y + a0.z*b3.z + a0.w*b3.w;
      acc10 += a1.x*b0.x + a1.y*b0.y + a1.z*b0.z + a1.w*b0.w;
      acc11 += a1.x*b1.x + a1.y*b1.y + a1.z*b1.z + a1.w*b1.w;
      acc12 += a1.x*b2.x + a1.y*b2.y + a1.z*b2.z + a1.w*b2.w;
      acc13 += a1.x*b3.x + a1.y*b3.y + a1.z*b3.z + a1.w*b3.w;
    }
  }
  float accs[2][4] = {{acc00,acc01,acc02,acc03},{acc10,acc11,acc12,acc13}};
  #pragma unroll
  for (int i = 0; i < 4; ++i) {
    int g = gtile + tx + 16*i;
    float bias = bih[g] + bhh[g];
    #pragma unroll
    for (int j = 0; j < 2; ++j) {
      int m = mtile + ty + 16*j;
      pre[((size_t)dir*640 + m)*1024 + g] = accs[j][i] + bias;
    }
  }
}

// ---------------- persistent bidirectional LSTM layer ----------------
// grid 16 x 1024. WG = (dir = blk>>3, chunk q = blk&7 -> units [32q,32q+32)).
// (B): thread (p=tid&127 local gate row, jq=tid>>7 col chunk), w_hh in 32 VGPRs.
// Sync: h published as 8B atomic {tag=step, f32 h} -> consumers spin on data
// directly (1 IF round trip, no flags, no release drain). Wave 0 finalizes gates
// (c-state in VGPRs); waves 1..15 gather next-step peers + prefetch pre (dbuf).
__global__ __launch_bounds__(1024) void k_lstm(
    const float* __restrict__ whhF, const float* __restrict__ whhB,
    const float* __restrict__ pre, float* __restrict__ out,
    u64* __restrict__ hg) {
  int wg  = blockIdx.x;
  int dir = wg >> 3;
  int q   = wg & 7;
  int tid = threadIdx.x;
  int p   = tid & 127;
  int jq  = tid >> 7;
  int jb  = jq * 32;
  const float* whh = dir ? whhB : whhF;

  __shared__ __align__(16) float h_lds[5*256];
  __shared__ float part[128*5*9];          // [row][b][jq] pad 9
  __shared__ float pre_lds[2][640];        // double-buffered pre[t] slice

  int gr = (p >> 5)*256 + q*32 + (p & 31);
  float w[32];
  #pragma unroll
  for (int m4 = 0; m4 < 8; ++m4) {
    float4 a = *(const float4*)(whh + (size_t)gr*256 + jb + m4*4);
    w[m4*4+0]=a.x; w[m4*4+1]=a.y; w[m4*4+2]=a.z; w[m4*4+3]=a.w;
  }
  for (int f = tid; f < 1280; f += 1024) h_lds[f] = 0.f;
  float c0 = 0.f, c1 = 0.f, c2 = 0.f;     // cell state, wave0 entries tid+{0,64,128}
  if (tid < 640) {                         // prefetch pre for step 0
    int b = tid >> 7, r = tid & 127;
    int grow = (r >> 5)*256 + q*32 + (r & 31);
    int t0 = dir ? (LL-1) : 0;
    pre_lds[0][tid] = pre[(((size_t)dir*LL + t0)*5 + b)*1024 + grow];
  }
  u64* hg_dir = hg + (size_t)dir * 2560;   // [2 parity][1280]
  __syncthreads();

  for (int s = 0; s < LL; ++s) {
    int t = dir ? (LL-1-s) : s;
    // (B) hidden GEMM partials from h_lds (broadcast reads, conflict-free)
    float acc[5];
    #pragma unroll
    for (int b = 0; b < 5; ++b) {
      const float4* h4 = (const float4*)&h_lds[b*256 + jb];
      float a = 0.f;
      #pragma unroll
      for (int m4 = 0; m4 < 8; ++m4) {
        float4 hv = h4[m4];
        a += w[m4*4]*hv.x + w[m4*4+1]*hv.y + w[m4*4+2]*hv.z + w[m4*4+3]*hv.w;
      }
      acc[b] = a;
    }
    #pragma unroll
    for (int b = 0; b < 5; ++b) part[(p*5 + b)*9 + jq] = acc[b];
    __syncthreads();
    int buf = s & 1;
    if (tid < 64) {
      // finalize 160 unit-batch entries on wave 0; publish {tag,h} immediately
      u64* hwr = hg_dir + (size_t)((s+1)&1) * 1280;
      #pragma unroll
      for (int r = 0; r < 3; ++r) {
        int e = tid + 64*r;
        if (e < 160) {
          int b = e >> 5, u = e & 31;
          float g[4];
          #pragma unroll
          for (int gate = 0; gate < 4; ++gate) {
            int rr = gate*32 + u;
            float sum = pre_lds[buf][b*128 + rr];
            #pragma unroll
            for (int m = 0; m < 8; ++m) sum += part[(rr*5 + b)*9 + m];
            g[gate] = sum;
          }
          float cold = (r==0) ? c0 : ((r==1) ? c1 : c2);
          float ig = sigf(g[0]), fg = sigf(g[1]), cc = tanhf(g[2]), og = sigf(g[3]);
          float cn = fg*cold + ig*cc;
          if (r==0) c0 = cn; else if (r==1) c1 = cn; else c2 = cn;
          float hv = og * tanhf(cn);
          out[((size_t)t*5 + b)*DD + dir*HH + q*32 + u] = hv;
          h_lds[b*256 + q*32 + u] = hv;
          union { float f; u32 i; } uv; uv.f = hv;
          u64 pk = ((u64)(u32)(s+1) << 32) | (u64)uv.i;
          __hip_atomic_store(&hwr[b*256 + q*32 + u], pk,
                             __ATOMIC_RELAXED, __HIP_MEMORY_SCOPE_AGENT);
        }
      }
    } else if (s + 1 < LL) {
      // waves 1..15: prefetch pre[t+1] and gather peer h for step s+1
      int idx2 = tid - 64;
      if (idx2 < 640) {
        int b = idx2 >> 7, r = idx2 & 127;
        int grow = (r >> 5)*256 + q*32 + (r & 31);
        int t1 = dir ? (LL-2-s) : (s+1);
        pre_lds[buf^1][idx2] = pre[(((size_t)dir*LL + t1)*5 + b)*1024 + grow];
      }
      const u64* hrd = hg_dir + (size_t)((s+1)&1) * 1280;
      u32 want = (u32)(s+1);
      for (int f = tid - 64; f < 1120; f += 960) {
        int pr = f / 160, rem = f % 160;
        int b = rem >> 5, u = rem & 31;
        int pch = pr + (pr >= q);
        int idx = b*256 + pch*32 + u;
        u64 v = __hip_atomic_load(&hrd[idx], __ATOMIC_RELAXED, __HIP_MEMORY_SCOPE_AGENT);
        while ((u32)(v >> 32) != want)
          v = __hip_atomic_load(&hrd[idx], __ATOMIC_RELAXED, __HIP_MEMORY_SCOPE_AGENT);
        union { u32 i; float f2; } uv; uv.i = (u32)v;
        h_lds[idx] = uv.f2;
      }
    }
    __syncthreads();
  }
}

// ---------------- attention epilogue (out layout [(t*5+b)][512]) ----------------
__global__ void k_attn(const float* __restrict__ out1, const float* __restrict__ csb,
                       float* __restrict__ outp) {
  int b = blockIdx.x, tid = threadIdx.x;   // 5 blocks x 256 threads
  __shared__ float cs[512];
  __shared__ float att[128];
  __shared__ float red[256];
  __shared__ float smax, ssum;
  cs[tid] = csb[tid]; cs[tid+256] = csb[tid+256];
  __syncthreads();
  {
    int t = tid & 127, half = tid >> 7;
    const float* row = out1 + ((size_t)t*5 + b)*DD + half*256;
    const float* c2 = cs + half*256;
    float a = 0.f;
    for (int d = 0; d < 256; d += 4) {
      float4 v = *(const float4*)(row + d);
      a += v.x*c2[d] + v.y*c2[d+1] + v.z*c2[d+2] + v.w*c2[d+3];
    }
    red[tid] = a;
  }
  __syncthreads();
  if (tid < 128) att[tid] = red[tid] + red[tid+128];
  __syncthreads();
  if (tid < 64) red[tid] = fmaxf(att[tid], att[tid+64]);
  __syncthreads();
  if (tid == 0) { float m = red[0]; for (int o = 1; o < 64; ++o) m = fmaxf(m, red[o]); smax = m; }
  __syncthreads();
  if (tid < 128) att[tid] = expf(att[tid] - smax);
  __syncthreads();
  if (tid < 64) red[tid] = att[tid] + att[tid+64];
  __syncthreads();
  if (tid == 0) { float s = 0.f; for (int o = 0; o < 64; ++o) s += red[o]; ssum = s; }
  __syncthreads();
  float inv = 1.0f / ssum;
  for (int d = tid; d < DD; d += 256) {
    float acc = 0.f;
    for (int t2 = 0; t2 < LL; ++t2) acc += att[t2] * out1[((size_t)t2*5 + b)*DD + d];
    outp[b*DD + d] = acc * inv;
  }
}

extern "C" void kernel_launch(void* const* d_in, const int* in_sizes, int n_in,
                              void* d_out, int out_size, void* d_ws, size_t ws_size,
                              hipStream_t stream) {
  (void)in_sizes; (void)n_in; (void)out_size; (void)ws_size;
  const float* ep   = (const float*)d_in[0];
  const float* qu   = (const float*)d_in[1];
  const float* cst  = (const float*)d_in[2];
  const float* ages = (const float*)d_in[3];
  const float* Wq   = (const float*)d_in[4];
  const float* bq   = (const float*)d_in[5];
  const float* Wk   = (const float*)d_in[6];
  const float *wih[4], *whh[4], *bih[4], *bhh[4];
  for (int l = 0; l < 4; ++l) {
    wih[l] = (const float*)d_in[8 + l*4 + 0];
    whh[l] = (const float*)d_in[8 + l*4 + 1];
    bih[l] = (const float*)d_in[8 + l*4 + 2];
    bhh[l] = (const float*)d_in[8 + l*4 + 3];
  }
  char* ws = (char*)d_ws;
  float* qp   = (float*)(ws + OFF_QP);
  float* uvec = (float*)(ws + OFF_U);
  float* sc   = (float*)(ws + OFF_SC);
  float* wsc  = (float*)(ws + OFF_WSC);
  int*   idx5 = (int*)  (ws + OFF_IDX);
  u64*   hg0  = (u64*)  (ws + OFF_HG);
  u64*   hg1  = hg0 + 5120;
  float* x0   = (float*)(ws + OFF_X0);
  float* pre  = (float*)(ws + OFF_PRE);
  float* out0 = (float*)(ws + OFF_OUT0);
  float* out1 = (float*)(ws + OFF_OUT1);

  k_qproj <<<4, 128, 0, stream>>>(Wq, qu, bq, qp);
  k_keyvec<<<4, 128, 0, stream>>>(Wk, qp, uvec);
  k_scores<<<NN, 256, 0, stream>>>(ep, uvec, sc);
  k_topk  <<<1, 1024, 0, stream>>>(sc, ages, idx5, wsc);
  k_gather<<<LL, 256, 0, stream>>>(ep, idx5, wsc, x0);

  k_pre <<<dim3(16,20,2), 256, 0, stream>>>(x0, wih[0], wih[1],
        bih[0], bhh[0], bih[1], bhh[1], pre);
  k_lstm<<<16, 1024, 0, stream>>>(whh[0], whh[1], pre, out0, hg0);

  k_pre <<<dim3(16,20,2), 256, 0, stream>>>(out0, wih[2], wih[3],
        bih[2], bhh[2], bih[3], bhh[3], pre);
  k_lstm<<<16, 1024, 0, stream>>>(whh[2], whh[3], pre, out1, hg1);

  k_attn<<<KK, 256, 0, stream>>>(out1, cst, (float*)d_out);
}